// Round 1
// baseline (196.450 us; speedup 1.0000x reference)
//
#include <hip/hip_runtime.h>

// SINDy-style fused polynomial feature + linear + bilinear form, per row:
//   out[n] = sum_f poly[f]*c[f] + sum_d derivs[d]*c[3+d]
//          + sum_{d,f} derivs[d]*poly[f]*c[6+3d+f]
// where poly = [u, u^2, u^3], derivs = big_u[n,1:4], c = coefficients*base_coeffs.
// Memory-bound: 16B in + 4B out per row.

__global__ __launch_bounds__(256) void sindy_kernel(
    const float4* __restrict__ big_u,
    const float*  __restrict__ coefficients,
    const float*  __restrict__ base_coeffs,
    float*        __restrict__ out,
    int n)
{
    int i = blockIdx.x * blockDim.x + threadIdx.x;
    if (i >= n) return;

    // Wave-uniform coefficient product (compiler emits scalar loads).
    float c[15];
#pragma unroll
    for (int k = 0; k < 15; ++k) c[k] = coefficients[k] * base_coeffs[k];

    float4 x = big_u[i];
    float u  = x.x, d1 = x.y, d2 = x.z, d3 = x.w;
    float u2 = u * u;
    float u3 = u2 * u;

    float r = u * c[0] + u2 * c[1] + u3 * c[2]
            + d1 * c[3] + d2 * c[4] + d3 * c[5]
            + d1 * (u * c[6]  + u2 * c[7]  + u3 * c[8])
            + d2 * (u * c[9]  + u2 * c[10] + u3 * c[11])
            + d3 * (u * c[12] + u2 * c[13] + u3 * c[14]);

    out[i] = r;
}

extern "C" void kernel_launch(void* const* d_in, const int* in_sizes, int n_in,
                              void* d_out, int out_size, void* d_ws, size_t ws_size,
                              hipStream_t stream) {
    const float4* big_u       = (const float4*)d_in[0];   // (N,4) f32 rows, 16B aligned
    const float*  coefficients = (const float*)d_in[1];   // (15,)
    const float*  base_coeffs  = (const float*)d_in[2];   // (15,)
    float* out = (float*)d_out;                           // (N,1) f32

    int n = in_sizes[0] / 4;  // number of rows
    const int block = 256;
    int grid = (n + block - 1) / block;
    sindy_kernel<<<grid, block, 0, stream>>>(big_u, coefficients, base_coeffs, out, n);
}

// Round 3
// 191.625 us; speedup vs baseline: 1.0252x; 1.0252x over previous
//
#include <hip/hip_runtime.h>

// SINDy-style fused polynomial feature + linear + bilinear form, per row:
//   out[n] = sum_f poly[f]*c[f] + sum_d derivs[d]*c[3+d]
//          + sum_{d,f} derivs[d]*poly[f]*c[6+3d+f]
// poly = [u, u^2, u^3], derivs = big_u[n,1:4], c = coefficients*base_coeffs.
// Memory-bound: 16B in + 4B out per row. Roofline ~25-30 us for 160 MB.
//
// ROWS_PER_THREAD=4, grid-strided: 4 independent 16B loads in flight per
// thread (MLP), perfect wave-level coalescing at each stride step.
// Nontemporal: streams with zero reuse; skip L2/L3 pollution.
// NOTE: __builtin_nontemporal_load needs a clang ext_vector_type pointer,
// not HIP_vector_type (float4) — hence fx4 below.

typedef float fx4 __attribute__((ext_vector_type(4)));

#define ROWS_PER_THREAD 4

__global__ __launch_bounds__(256) void sindy_kernel(
    const fx4* __restrict__ big_u,
    const float* __restrict__ coefficients,
    const float* __restrict__ base_coeffs,
    float* __restrict__ out,
    int n)
{
    // Wave-uniform coefficient product (scalar loads, cached).
    float c[15];
#pragma unroll
    for (int k = 0; k < 15; ++k) c[k] = coefficients[k] * base_coeffs[k];

    const int stride = gridDim.x * blockDim.x;
    int i = blockIdx.x * blockDim.x + threadIdx.x;

    // Issue all loads first (independent, nontemporal), then compute.
    fx4 x[ROWS_PER_THREAD];
    int idx[ROWS_PER_THREAD];
#pragma unroll
    for (int r = 0; r < ROWS_PER_THREAD; ++r) {
        idx[r] = i + r * stride;
        if (idx[r] < n) x[r] = __builtin_nontemporal_load(&big_u[idx[r]]);
    }

#pragma unroll
    for (int r = 0; r < ROWS_PER_THREAD; ++r) {
        if (idx[r] >= n) continue;
        float u  = x[r].x, d1 = x[r].y, d2 = x[r].z, d3 = x[r].w;
        float u2 = u * u;
        float u3 = u2 * u;

        float res = u * c[0] + u2 * c[1] + u3 * c[2]
                  + d1 * c[3] + d2 * c[4] + d3 * c[5]
                  + d1 * (u * c[6]  + u2 * c[7]  + u3 * c[8])
                  + d2 * (u * c[9]  + u2 * c[10] + u3 * c[11])
                  + d3 * (u * c[12] + u2 * c[13] + u3 * c[14]);

        __builtin_nontemporal_store(res, &out[idx[r]]);
    }
}

extern "C" void kernel_launch(void* const* d_in, const int* in_sizes, int n_in,
                              void* d_out, int out_size, void* d_ws, size_t ws_size,
                              hipStream_t stream) {
    const fx4*   big_u        = (const fx4*)d_in[0];    // (N,4) f32 rows, 16B aligned
    const float* coefficients = (const float*)d_in[1];  // (15,)
    const float* base_coeffs  = (const float*)d_in[2];  // (15,)
    float* out = (float*)d_out;                         // (N,1) f32

    int n = in_sizes[0] / 4;  // number of rows
    const int block = 256;
    int threads_needed = (n + ROWS_PER_THREAD - 1) / ROWS_PER_THREAD;
    int grid = (threads_needed + block - 1) / block;
    sindy_kernel<<<grid, block, 0, stream>>>(big_u, coefficients, base_coeffs, out, n);
}